// Round 4
// baseline (653.554 us; speedup 1.0000x reference)
//
#include <hip/hip_runtime.h>
#include <hip/hip_bf16.h>

#define G_ 2048
#define NPG_ 128
#define INC_ 151
#define HID_ 64
#define NNODES_ (G_ * NPG_)      // 262144
#define NEDGES_ 2097152

typedef __hip_bfloat16 bf16;
typedef short bf16x8v __attribute__((ext_vector_type(8)));
typedef float f32x4 __attribute__((ext_vector_type(4)));

static __device__ __forceinline__ __hip_bfloat162 f2bf2(float a, float b) {
    __hip_bfloat162 r;
    r.x = __float2bfloat16(a);
    r.y = __float2bfloat16(b);
    return r;
}

// ---------------------------------------------------------------------------
// K0: W1 [151][64] fp32 -> Bt [64 n][168 k] bf16 (k>=151 zero-padded)
// ---------------------------------------------------------------------------
__global__ void __launch_bounds__(256) k0_prep(const float* __restrict__ W1,
                                              bf16* __restrict__ Bt) {
    int i = blockIdx.x * 256 + threadIdx.x;
    if (i >= 64 * 168) return;
    int n = i / 168, k = i - n * 168;
    float v = (k < 151) ? W1[k * 64 + n] : 0.f;
    Bt[i] = __float2bfloat16(v);
}

// ---------------------------------------------------------------------------
// K1 (MFMA): h = x @ W1 bf16, plus as_[n]=h.att_src, ad_[n]=h.att_dst.
// 64 rows/block, 4 waves; wave -> 16 rows x 4 N-tiles, K=160 (5 MFMA steps).
// A staged as bf16 LDS stride 168 (43 KB total LDS -> 3 blocks/CU).
// ---------------------------------------------------------------------------
__global__ void __launch_bounds__(256) k1_mfma(
        const float* __restrict__ x, const bf16* __restrict__ Bt,
        const float* __restrict__ att_src, const float* __restrict__ att_dst,
        bf16* __restrict__ h, float* __restrict__ as_, float* __restrict__ ad_) {
    __shared__ __align__(16) bf16 Asb[64 * 168];
    __shared__ __align__(16) bf16 Bs[64 * 168];
    const int tid = threadIdx.x;
    const int rowbase = blockIdx.x * 64;

    // stage Bs (21504 B)
    {
        const uint4* s = (const uint4*)Bt;
        uint4* d = (uint4*)Bs;
        for (int i = tid; i < 1344; i += 256) d[i] = s[i];
    }
    // zero As pad cols 151..167
    for (int i = tid; i < 64 * 17; i += 256) {
        int r = i / 17, c = 151 + (i - r * 17);
        Asb[r * 168 + c] = __float2bfloat16(0.f);
    }
    // stage As: 64*151 = 9664 floats, coalesced float4 reads, bf16 scatter
    {
        const float4* xg = (const float4*)(x + (size_t)rowbase * 151);
        for (int i4 = tid; i4 < 2416; i4 += 256) {
            float4 v = xg[i4];
            float vals[4] = {v.x, v.y, v.z, v.w};
            int li = i4 * 4;
#pragma unroll
            for (int e = 0; e < 4; e++) {
                int idx = li + e;
                int r = idx / 151;
                int c = idx - r * 151;
                Asb[r * 168 + c] = __float2bfloat16(vals[e]);
            }
        }
    }
    __syncthreads();

    const int wv = tid >> 6, lane = tid & 63;
    const int quad = lane >> 4, m = lane & 15;

    f32x4 acc[4];
#pragma unroll
    for (int t = 0; t < 4; t++) acc[t] = (f32x4){0.f, 0.f, 0.f, 0.f};

    const bf16* Arow = &Asb[(wv * 16 + m) * 168];
#pragma unroll
    for (int ks = 0; ks < 5; ks++) {
        const int k0 = ks * 32 + quad * 8;
        bf16x8v af = *(const bf16x8v*)&Arow[k0];
#pragma unroll
        for (int t = 0; t < 4; t++) {
            bf16x8v bfr = *(const bf16x8v*)&Bs[(t * 16 + m) * 168 + k0];
            acc[t] = __builtin_amdgcn_mfma_f32_16x16x32_bf16(af, bfr, acc[t], 0, 0, 0);
        }
    }

    // epilogue
    float as4[4], ad4[4];
#pragma unroll
    for (int t = 0; t < 4; t++) {
        as4[t] = att_src[t * 16 + m];
        ad4[t] = att_dst[t * 16 + m];
    }
#pragma unroll
    for (int r = 0; r < 4; r++) {
        float s = acc[0][r] * as4[0] + acc[1][r] * as4[1] +
                  acc[2][r] * as4[2] + acc[3][r] * as4[3];
        float d = acc[0][r] * ad4[0] + acc[1][r] * ad4[1] +
                  acc[2][r] * ad4[2] + acc[3][r] * ad4[3];
#pragma unroll
        for (int off = 1; off <= 8; off <<= 1) {
            s += __shfl_xor(s, off);
            d += __shfl_xor(d, off);
        }
        const int node = rowbase + wv * 16 + quad * 4 + r;
        if (m == 0) { as_[node] = s; ad_[node] = d; }
#pragma unroll
        for (int t = 0; t < 4; t++) {
            float val = acc[t][r];
            float oth = __shfl_xor(val, 1);
            if (!(lane & 1)) {
                unsigned short lo = __builtin_bit_cast(unsigned short, __float2bfloat16(val));
                unsigned short hi = __builtin_bit_cast(unsigned short, __float2bfloat16(oth));
                unsigned int u = ((unsigned int)hi << 16) | lo;
                *(unsigned int*)&h[(size_t)node * 64 + t * 16 + m] = u;
            }
        }
    }
}

// ---------------------------------------------------------------------------
// K_hist: per-graph edge counts (LDS histogram per block, then global adds)
// ---------------------------------------------------------------------------
__global__ void __launch_bounds__(256) k_hist(const int* __restrict__ ei,
                                              unsigned int* __restrict__ gcount) {
    __shared__ unsigned int hist[G_];
    const int tid = threadIdx.x;
    for (int i = tid; i < G_; i += 256) hist[i] = 0;
    __syncthreads();
    const int e0 = blockIdx.x * 8192;
    for (int e = e0 + tid; e < e0 + 8192; e += 256)
        atomicAdd(&hist[ei[e] >> 7], 1u);
    __syncthreads();
    for (int i = tid; i < G_; i += 256) {
        unsigned int c = hist[i];
        if (c) atomicAdd(&gcount[i], c);
    }
}

// ---------------------------------------------------------------------------
// K_scan: exclusive prefix sum of gcount[2048] -> base[2049], cursor[2048]
// ---------------------------------------------------------------------------
__global__ void __launch_bounds__(256) k_scan(const unsigned int* __restrict__ gcount,
                                              unsigned int* __restrict__ base,
                                              unsigned int* __restrict__ cursor) {
    __shared__ unsigned int ssum[256];
    const int tid = threadIdx.x;
    unsigned int v[8], tot = 0;
#pragma unroll
    for (int j = 0; j < 8; j++) { v[j] = gcount[tid * 8 + j]; tot += v[j]; }
    ssum[tid] = tot;
    __syncthreads();
    for (int off = 1; off < 256; off <<= 1) {
        unsigned int t = (tid >= off) ? ssum[tid - off] : 0;
        __syncthreads();
        ssum[tid] += t;
        __syncthreads();
    }
    unsigned int run = ssum[tid] - tot;   // exclusive
#pragma unroll
    for (int j = 0; j < 8; j++) {
        base[tid * 8 + j] = run;
        cursor[tid * 8 + j] = run;
        run += v[j];
    }
    if (tid == 255) base[2048] = run;
}

// ---------------------------------------------------------------------------
// K_scatter: bucket edges by graph as packed u16 (src_l<<7 | dst_l)
// ---------------------------------------------------------------------------
__global__ void __launch_bounds__(256) k_scatter(const int* __restrict__ ei,
                                                 unsigned int* __restrict__ cursor,
                                                 unsigned short* __restrict__ eb) {
    int e = blockIdx.x * 256 + threadIdx.x;
    int s = ei[e];
    int d = ei[NEDGES_ + e];
    int g = s >> 7;
    unsigned int pos = atomicAdd(&cursor[g], 1u);
    eb[pos] = (unsigned short)(((s & 127) << 7) | (d & 127));
}

// ---------------------------------------------------------------------------
// K3: one graph per block. Build A in LDS from bucketed edges (two 64-row
// fp32 half-passes), normalize, then At^T @ h with fused linear+sigmoid.
// LDS: At bf16 32KB + S fp32 32KB (build scratch / colsum scratch / h stage).
// ---------------------------------------------------------------------------
__global__ void __launch_bounds__(256) k3_graph(
        const unsigned short* __restrict__ eb, const unsigned int* __restrict__ base,
        const bf16* __restrict__ h,
        const float* __restrict__ as_, const float* __restrict__ ad_,
        const float* __restrict__ b1, const float* __restrict__ Wlin,
        const float* __restrict__ blin, float* __restrict__ out) {
    __shared__ __align__(16) bf16 At[128 * 128];   // [src j][dst i]
    __shared__ __align__(16) float S[64 * 128];    // 32 KB multi-purpose
    const int tid = threadIdx.x;
    const int g = blockIdx.x;
    const unsigned int gb = base[g], ge = base[g + 1];
    const float* asg = as_ + (g << 7);
    const float* adg = ad_ + (g << 7);
    const bf16* hg = h + ((size_t)g << 13);

    // build A = exp(leakyrelu(alpha)) in two 64-src-row half passes
#pragma unroll 1
    for (int p = 0; p < 2; p++) {
        for (int i = tid; i < 2048; i += 256)
            ((float4*)S)[i] = make_float4(0.f, 0.f, 0.f, 0.f);
        __syncthreads();
        for (unsigned int idx = gb + tid; idx < ge; idx += 256) {
            unsigned int v = eb[idx];
            int sl = v >> 7, dl = v & 127;
            if ((sl >> 6) == p) {
                float a = asg[sl] + adg[dl];
                a = (a > 0.f) ? a : 0.2f * a;
                atomicAdd(&S[((sl & 63) << 7) + dl], __expf(a));
            }
        }
        __syncthreads();
        for (int i = tid; i < 2048; i += 256) {
            float4 v = ((const float4*)S)[i];
            __hip_bfloat162* d2 = (__hip_bfloat162*)(At + p * 8192 + i * 4);
            d2[0] = f2bf2(v.x, v.y);
            d2[1] = f2bf2(v.z, v.w);
        }
        __syncthreads();
    }

    // self loops
    if (tid < 128) {
        float a = asg[tid] + adg[tid];
        a = (a > 0.f) ? a : 0.2f * a;
        float ex = __expf(a);
        At[tid * 128 + tid] =
            __float2bfloat16(__bfloat162float(At[tid * 128 + tid]) + ex);
    }
    __syncthreads();

    // column sums -> normalize columns in place
    const int ic = tid & 127, jh = tid >> 7;
    {
        float pp = 0.f;
        for (int j = jh * 64; j < jh * 64 + 64; j++)
            pp += __bfloat162float(At[j * 128 + ic]);
        S[tid] = pp;
    }
    __syncthreads();
    {
        float inv = 1.f / (S[ic] + S[ic + 128]);
        for (int j = jh * 64; j < jh * 64 + 64; j++) {
            int ai = j * 128 + ic;
            At[ai] = __float2bfloat16(__bfloat162float(At[ai]) * inv);
        }
    }
    __syncthreads();

    // stage h -> fp32 S
    for (int idx = tid; idx < 4096; idx += 256) {
        __hip_bfloat162 hv = ((const __hip_bfloat162*)hg)[idx];
        float2 f2 = __bfloat1622float2(hv);
        *(float2*)&S[idx * 2] = f2;
    }
    __syncthreads();

    // matmul: wave wv -> rows i = (wv&1)*64 + lane, feats f0 = (wv>>1)*32
    const int wv = tid >> 6, lane = tid & 63;
    const int i = ((wv & 1) << 6) | lane;
    const int f0 = (wv >> 1) << 5;
    float acc[32];
#pragma unroll
    for (int q = 0; q < 32; q++) acc[q] = 0.f;

    for (int j = 0; j < 128; j++) {
        float a = __bfloat162float(At[j * 128 + i]);
        const float4* hp = (const float4*)&S[(j << 6) + f0];
#pragma unroll
        for (int q = 0; q < 8; q++) {
            float4 hv = hp[q];
            acc[4 * q + 0] += a * hv.x;
            acc[4 * q + 1] += a * hv.y;
            acc[4 * q + 2] += a * hv.z;
            acc[4 * q + 3] += a * hv.w;
        }
    }

    // epilogue: relu(acc + b1) . Wlin
    float p = 0.f;
    const float* wl = Wlin + i * 64 + f0;
#pragma unroll
    for (int q = 0; q < 8; q++) {
        float4 b4 = *(const float4*)&b1[f0 + 4 * q];
        float4 w4 = *(const float4*)&wl[4 * q];
        float o0 = acc[4 * q + 0] + b4.x; o0 = o0 > 0.f ? o0 : 0.f;
        float o1 = acc[4 * q + 1] + b4.y; o1 = o1 > 0.f ? o1 : 0.f;
        float o2 = acc[4 * q + 2] + b4.z; o2 = o2 > 0.f ? o2 : 0.f;
        float o3 = acc[4 * q + 3] + b4.w; o3 = o3 > 0.f ? o3 : 0.f;
        p += o0 * w4.x + o1 * w4.y + o2 * w4.z + o3 * w4.w;
    }
#pragma unroll
    for (int off = 32; off; off >>= 1) p += __shfl_xor(p, off);

    __syncthreads();
    if (lane == 0) S[wv] = p;
    __syncthreads();
    if (tid == 0) {
        float logit = S[0] + S[1] + S[2] + S[3] + blin[0];
        out[g] = 1.f / (1.f + __expf(-logit));
    }
}

// ---------------------------------------------------------------------------
extern "C" void kernel_launch(void* const* d_in, const int* in_sizes, int n_in,
                              void* d_out, int out_size, void* d_ws, size_t ws_size,
                              hipStream_t stream) {
    (void)in_sizes; (void)n_in; (void)out_size; (void)ws_size;
    const float* x       = (const float*)d_in[0];
    const int*   ei      = (const int*)d_in[1];
    const float* W1      = (const float*)d_in[2];
    const float* att_src = (const float*)d_in[3];
    const float* att_dst = (const float*)d_in[4];
    const float* b1      = (const float*)d_in[5];
    const float* Wlin    = (const float*)d_in[6];
    const float* blin    = (const float*)d_in[7];
    float* out = (float*)d_out;

    char* ws = (char*)d_ws;
    bf16*           h      = (bf16*)ws;                      // 33,554,432 B
    float*          as_    = (float*)(ws + 33554432);        // 1 MB
    float*          ad_    = (float*)(ws + 34603008);        // 1 MB
    bf16*           Bt     = (bf16*)(ws + 35651584);         // 21,504 B (pad 64K)
    unsigned int*   gcount = (unsigned int*)(ws + 35717120); // 8 KB
    unsigned int*   base   = (unsigned int*)(ws + 35725312); // 8,196 B (pad 12K)
    unsigned int*   cursor = (unsigned int*)(ws + 35737600); // 8 KB
    unsigned short* eb     = (unsigned short*)(ws + 35745792); // 4,194,304 B

    (void)hipMemsetAsync(gcount, 0, G_ * sizeof(unsigned int), stream);
    k0_prep<<<42, 256, 0, stream>>>(W1, Bt);
    k1_mfma<<<NNODES_ / 64, 256, 0, stream>>>(x, Bt, att_src, att_dst, h, as_, ad_);
    k_hist<<<NEDGES_ / 8192, 256, 0, stream>>>(ei, gcount);
    k_scan<<<1, 256, 0, stream>>>(gcount, base, cursor);
    k_scatter<<<NEDGES_ / 256, 256, 0, stream>>>(ei, cursor, eb);
    k3_graph<<<G_, 256, 0, stream>>>(eb, base, h, as_, ad_, b1, Wlin, blin, out);
}

// Round 5
// 469.516 us; speedup vs baseline: 1.3920x; 1.3920x over previous
//
#include <hip/hip_runtime.h>
#include <hip/hip_bf16.h>

#define G_ 2048
#define NPG_ 128
#define INC_ 151
#define HID_ 64
#define NNODES_ (G_ * NPG_)      // 262144
#define NEDGES_ 2097152

typedef __hip_bfloat16 bf16;
typedef short bf16x8v __attribute__((ext_vector_type(8)));
typedef float f32x4 __attribute__((ext_vector_type(4)));

static __device__ __forceinline__ short f2bs(float f) {
    __hip_bfloat16 b = __float2bfloat16(f);
    return __builtin_bit_cast(short, b);
}
static __device__ __forceinline__ float b2f(short s) {
    unsigned int u = ((unsigned int)(unsigned short)s) << 16;
    return __builtin_bit_cast(float, u);
}

// ---------------------------------------------------------------------------
// K0: W1 [151][64] fp32 -> Bt [64 n][168 k] bf16 (k>=151 zero-padded)
// ---------------------------------------------------------------------------
__global__ void __launch_bounds__(256) k0_prep(const float* __restrict__ W1,
                                              bf16* __restrict__ Bt) {
    int i = blockIdx.x * 256 + threadIdx.x;
    if (i >= 64 * 168) return;
    int n = i / 168, k = i - n * 168;
    float v = (k < 151) ? W1[k * 64 + n] : 0.f;
    Bt[i] = __float2bfloat16(v);
}

// ---------------------------------------------------------------------------
// K1 (MFMA): h = x @ W1 bf16, plus as_[n]=h.att_src, ad_[n]=h.att_dst.
// ---------------------------------------------------------------------------
__global__ void __launch_bounds__(256) k1_mfma(
        const float* __restrict__ x, const bf16* __restrict__ Bt,
        const float* __restrict__ att_src, const float* __restrict__ att_dst,
        bf16* __restrict__ h, float* __restrict__ as_, float* __restrict__ ad_) {
    __shared__ __align__(16) bf16 Asb[64 * 168];
    __shared__ __align__(16) bf16 Bs[64 * 168];
    const int tid = threadIdx.x;
    const int rowbase = blockIdx.x * 64;

    {
        const uint4* s = (const uint4*)Bt;
        uint4* d = (uint4*)Bs;
        for (int i = tid; i < 1344; i += 256) d[i] = s[i];
    }
    for (int i = tid; i < 64 * 17; i += 256) {
        int r = i / 17, c = 151 + (i - r * 17);
        Asb[r * 168 + c] = __float2bfloat16(0.f);
    }
    {
        const float4* xg = (const float4*)(x + (size_t)rowbase * 151);
        for (int i4 = tid; i4 < 2416; i4 += 256) {
            float4 v = xg[i4];
            float vals[4] = {v.x, v.y, v.z, v.w};
            int li = i4 * 4;
#pragma unroll
            for (int e = 0; e < 4; e++) {
                int idx = li + e;
                int r = idx / 151;
                int c = idx - r * 151;
                Asb[r * 168 + c] = __float2bfloat16(vals[e]);
            }
        }
    }
    __syncthreads();

    const int wv = tid >> 6, lane = tid & 63;
    const int quad = lane >> 4, m = lane & 15;

    f32x4 acc[4];
#pragma unroll
    for (int t = 0; t < 4; t++) acc[t] = (f32x4){0.f, 0.f, 0.f, 0.f};

    const bf16* Arow = &Asb[(wv * 16 + m) * 168];
#pragma unroll
    for (int ks = 0; ks < 5; ks++) {
        const int k0 = ks * 32 + quad * 8;
        bf16x8v af = *(const bf16x8v*)&Arow[k0];
#pragma unroll
        for (int t = 0; t < 4; t++) {
            bf16x8v bfr = *(const bf16x8v*)&Bs[(t * 16 + m) * 168 + k0];
            acc[t] = __builtin_amdgcn_mfma_f32_16x16x32_bf16(af, bfr, acc[t], 0, 0, 0);
        }
    }

    float as4[4], ad4[4];
#pragma unroll
    for (int t = 0; t < 4; t++) {
        as4[t] = att_src[t * 16 + m];
        ad4[t] = att_dst[t * 16 + m];
    }
#pragma unroll
    for (int r = 0; r < 4; r++) {
        float s = acc[0][r] * as4[0] + acc[1][r] * as4[1] +
                  acc[2][r] * as4[2] + acc[3][r] * as4[3];
        float d = acc[0][r] * ad4[0] + acc[1][r] * ad4[1] +
                  acc[2][r] * ad4[2] + acc[3][r] * ad4[3];
#pragma unroll
        for (int off = 1; off <= 8; off <<= 1) {
            s += __shfl_xor(s, off);
            d += __shfl_xor(d, off);
        }
        const int node = rowbase + wv * 16 + quad * 4 + r;
        if (m == 0) { as_[node] = s; ad_[node] = d; }
#pragma unroll
        for (int t = 0; t < 4; t++) {
            float val = acc[t][r];
            float oth = __shfl_xor(val, 1);
            if (!(lane & 1)) {
                unsigned short lo = (unsigned short)f2bs(val);
                unsigned short hi = (unsigned short)f2bs(oth);
                unsigned int u = ((unsigned int)hi << 16) | lo;
                *(unsigned int*)&h[(size_t)node * 64 + t * 16 + m] = u;
            }
        }
    }
}

// ---------------------------------------------------------------------------
// kA: per-block (64 blocks x 32768 edges) LDS histogram -> bcount[b][g]
// ---------------------------------------------------------------------------
__global__ void __launch_bounds__(256) kA_hist(const int* __restrict__ ei,
                                               unsigned int* __restrict__ bcount) {
    __shared__ unsigned int hist[G_];
    const int tid = threadIdx.x;
    for (int i = tid; i < G_; i += 256) hist[i] = 0;
    __syncthreads();
    const int e0 = blockIdx.x * 32768;
    for (int e = e0 + tid; e < e0 + 32768; e += 256)
        atomicAdd(&hist[ei[e] >> 7], 1u);
    __syncthreads();
    unsigned int* dst = bcount + blockIdx.x * G_;
    for (int i = tid; i < G_; i += 256) dst[i] = hist[i];
}

// ---------------------------------------------------------------------------
// kB: in-place convert bcount[b][g] -> per-block relative offsets; write base[g]
// (exclusive scan of per-graph totals), base[2048] = E.  1 block, 256 threads.
// ---------------------------------------------------------------------------
__global__ void __launch_bounds__(256) kB_scan(unsigned int* __restrict__ bcount,
                                               unsigned int* __restrict__ base) {
    __shared__ unsigned int ssum[256];
    const int tid = threadIdx.x;
    const int t8 = tid * 8;
    unsigned int run8[8] = {0, 0, 0, 0, 0, 0, 0, 0};
#pragma unroll 1
    for (int b = 0; b < 64; b++) {
        unsigned int* p = bcount + b * G_ + t8;
#pragma unroll
        for (int j = 0; j < 8; j++) {
            unsigned int c = p[j];
            p[j] = run8[j];          // relative offset of block b within graph g
            run8[j] += c;
        }
    }
    unsigned int T = 0;
#pragma unroll
    for (int j = 0; j < 8; j++) T += run8[j];
    ssum[tid] = T;
    __syncthreads();
    for (int off = 1; off < 256; off <<= 1) {
        unsigned int t = (tid >= off) ? ssum[tid - off] : 0;
        __syncthreads();
        ssum[tid] += t;
        __syncthreads();
    }
    unsigned int run = ssum[tid] - T;   // exclusive thread base
#pragma unroll
    for (int j = 0; j < 8; j++) {
        base[t8 + j] = run;
        run += run8[j];
    }
    if (tid == 255) base[G_] = run;
}

// ---------------------------------------------------------------------------
// kC: scatter edges to buckets using block-local LDS cursors (no global atomics)
// ---------------------------------------------------------------------------
__global__ void __launch_bounds__(256) kC_scatter(const int* __restrict__ ei,
                                                  const unsigned int* __restrict__ bcount,
                                                  const unsigned int* __restrict__ base,
                                                  unsigned short* __restrict__ eb) {
    __shared__ unsigned int cur[G_];
    const int tid = threadIdx.x;
    const int b = blockIdx.x;
    for (int i = tid; i < G_; i += 256) cur[i] = base[i] + bcount[b * G_ + i];
    __syncthreads();
    const int e0 = b * 32768;
    for (int e = e0 + tid; e < e0 + 32768; e += 256) {
        int s = ei[e];
        int d = ei[NEDGES_ + e];
        int g = s >> 7;
        unsigned int pos = atomicAdd(&cur[g], 1u);
        eb[pos] = (unsigned short)(((s & 127) << 7) | (d & 127));
    }
}

// ---------------------------------------------------------------------------
// K3: one graph per block, MFMA version.
// LDS (52224 B static, 3 blocks/CU):
//   Ab  bf16 [128 dst][136]   bytes 0..34816   (stride 136 = conflict-free+aligned)
//   S   fp32 [32][128]        bytes 34816..51200   (build accum / rowsum scratch)
//   hT  bf16 [64 f][136 j]    bytes 34816..52224   (staged after normalize)
//   ec  u16  [2048]           bytes 30720..34816   (edge cache; dies in pass-3 convert)
// ---------------------------------------------------------------------------
__global__ void __launch_bounds__(256) k3_graph(
        const unsigned short* __restrict__ eb, const unsigned int* __restrict__ base,
        const bf16* __restrict__ h,
        const float* __restrict__ as_, const float* __restrict__ ad_,
        const float* __restrict__ b1, const float* __restrict__ Wlin,
        const float* __restrict__ blin, float* __restrict__ out) {
    __shared__ __align__(16) unsigned char lds[52224];
    short* Ab = (short*)lds;                               // [128][136]
    float* S = (float*)(lds + 34816);                      // [32][128]
    short* hT = (short*)(lds + 34816);                     // [64][136]
    unsigned short* ec = (unsigned short*)(lds + 30720);   // [2048]

    const int tid = threadIdx.x;
    const int g = blockIdx.x;
    const unsigned int gb = base[g], ge = base[g + 1];
    const float* asg = as_ + (g << 7);
    const float* adg = ad_ + (g << 7);
    const unsigned int* hgu = (const unsigned int*)(h + ((size_t)g << 13));

    // cache this graph's edges in LDS (cap 2048; overflow read from global)
    const unsigned int cnt = ge - gb;
    const unsigned int ccnt = cnt > 2048u ? 2048u : cnt;
    for (unsigned int k = tid; k < ccnt; k += 256) ec[k] = eb[gb + k];
    __syncthreads();

    // build A[dst][src] = exp(leakyrelu(alpha)) in 4 passes of 32 dst rows
#pragma unroll 1
    for (int p = 0; p < 4; p++) {
        for (int i = tid; i < 1024; i += 256)
            ((float4*)S)[i] = make_float4(0.f, 0.f, 0.f, 0.f);
        __syncthreads();
        for (unsigned int k = tid; k < ccnt; k += 256) {
            unsigned int v = ec[k];
            int sl = v >> 7, dl = v & 127;
            if ((dl >> 5) == p) {
                float a = asg[sl] + adg[dl];
                a = (a > 0.f) ? a : 0.2f * a;
                atomicAdd(&S[((dl & 31) << 7) + sl], __expf(a));
            }
        }
        for (unsigned int k = gb + ccnt + tid; k < ge; k += 256) {  // overflow (rare)
            unsigned int v = eb[k];
            int sl = v >> 7, dl = v & 127;
            if ((dl >> 5) == p) {
                float a = asg[sl] + adg[dl];
                a = (a > 0.f) ? a : 0.2f * a;
                atomicAdd(&S[((dl & 31) << 7) + sl], __expf(a));
            }
        }
        __syncthreads();
        // convert S[32][128] -> Ab rows 32p..32p+31 (bf16, stride 136)
        for (int c = tid; c < 512; c += 256) {
            int r = c >> 4;
            int col = (c & 15) << 3;
            float4 v0 = ((const float4*)S)[c * 2];
            float4 v1 = ((const float4*)S)[c * 2 + 1];
            bf16x8v pk = {f2bs(v0.x), f2bs(v0.y), f2bs(v0.z), f2bs(v0.w),
                          f2bs(v1.x), f2bs(v1.y), f2bs(v1.z), f2bs(v1.w)};
            *(bf16x8v*)&Ab[(32 * p + r) * 136 + col] = pk;
        }
        __syncthreads();
    }

    // self loops
    if (tid < 128) {
        float a = asg[tid] + adg[tid];
        a = (a > 0.f) ? a : 0.2f * a;
        Ab[tid * 136 + tid] = f2bs(b2f(Ab[tid * 136 + tid]) + __expf(a));
    }
    __syncthreads();

    // row sums (denominators): 2 threads/row, 64 contiguous each
    const int ri = tid >> 1, rh = tid & 1;
    {
        const bf16x8v* rp = (const bf16x8v*)&Ab[ri * 136 + rh * 64];
        float s = 0.f;
#pragma unroll
        for (int q8 = 0; q8 < 8; q8++) {
            bf16x8v v = rp[q8];
#pragma unroll
            for (int e = 0; e < 8; e++) s += b2f(v[e]);
        }
        S[tid] = s;
    }
    __syncthreads();
    {
        float inv = 1.f / (S[ri * 2] + S[ri * 2 + 1]);
        bf16x8v* wp = (bf16x8v*)&Ab[ri * 136 + rh * 64];
#pragma unroll
        for (int q8 = 0; q8 < 8; q8++) {
            bf16x8v v = wp[q8];
            bf16x8v o;
#pragma unroll
            for (int e = 0; e < 8; e++) o[e] = f2bs(b2f(v[e]) * inv);
            wp[q8] = o;
        }
    }
    __syncthreads();

    // stage hT[f][j] (transposed, stride 136) from h[j][f]
    for (int idx = tid; idx < 4096; idx += 256) {
        unsigned int u = hgu[idx];
        int j = idx >> 5, f2 = idx & 31;
        hT[(2 * f2) * 136 + j] = (short)(u & 0xFFFF);
        hT[(2 * f2 + 1) * 136 + j] = (short)(u >> 16);
    }
    __syncthreads();

    // MFMA: wave w -> rows i0=w*32 (2 M-tiles), 4 N-tiles, K=128 (4 steps)
    const int w = tid >> 6, lane = tid & 63;
    const int quad = lane >> 4, m = lane & 15;
    const int i0 = w * 32;
    f32x4 acc[2][4];
#pragma unroll
    for (int mt = 0; mt < 2; mt++)
#pragma unroll
        for (int nt = 0; nt < 4; nt++) acc[mt][nt] = (f32x4){0.f, 0.f, 0.f, 0.f};

#pragma unroll
    for (int ks = 0; ks < 4; ks++) {
        const int k0 = ks * 32 + quad * 8;
        bf16x8v a0 = *(const bf16x8v*)&Ab[(i0 + m) * 136 + k0];
        bf16x8v a1 = *(const bf16x8v*)&Ab[(i0 + 16 + m) * 136 + k0];
#pragma unroll
        for (int nt = 0; nt < 4; nt++) {
            bf16x8v bfr = *(const bf16x8v*)&hT[(nt * 16 + m) * 136 + k0];
            acc[0][nt] = __builtin_amdgcn_mfma_f32_16x16x32_bf16(a0, bfr, acc[0][nt], 0, 0, 0);
            acc[1][nt] = __builtin_amdgcn_mfma_f32_16x16x32_bf16(a1, bfr, acc[1][nt], 0, 0, 0);
        }
    }

    // epilogue: relu(out + b1) . Wlin
    float p = 0.f;
#pragma unroll
    for (int nt = 0; nt < 4; nt++) {
        float bb = b1[nt * 16 + m];
#pragma unroll
        for (int mt = 0; mt < 2; mt++) {
#pragma unroll
            for (int r = 0; r < 4; r++) {
                int il = i0 + mt * 16 + quad * 4 + r;
                float v = acc[mt][nt][r] + bb;
                v = v > 0.f ? v : 0.f;
                p += v * Wlin[il * 64 + nt * 16 + m];
            }
        }
    }
#pragma unroll
    for (int off = 32; off; off >>= 1) p += __shfl_xor(p, off);

    __syncthreads();
    if (lane == 0) S[w] = p;
    __syncthreads();
    if (tid == 0) {
        float logit = S[0] + S[1] + S[2] + S[3] + blin[0];
        out[g] = 1.f / (1.f + __expf(-logit));
    }
}

// ---------------------------------------------------------------------------
extern "C" void kernel_launch(void* const* d_in, const int* in_sizes, int n_in,
                              void* d_out, int out_size, void* d_ws, size_t ws_size,
                              hipStream_t stream) {
    (void)in_sizes; (void)n_in; (void)out_size; (void)ws_size;
    const float* x       = (const float*)d_in[0];
    const int*   ei      = (const int*)d_in[1];
    const float* W1      = (const float*)d_in[2];
    const float* att_src = (const float*)d_in[3];
    const float* att_dst = (const float*)d_in[4];
    const float* b1      = (const float*)d_in[5];
    const float* Wlin    = (const float*)d_in[6];
    const float* blin    = (const float*)d_in[7];
    float* out = (float*)d_out;

    char* ws = (char*)d_ws;
    bf16*           h      = (bf16*)ws;                        // 33,554,432 B
    float*          as_    = (float*)(ws + 33554432);          // 1 MB
    float*          ad_    = (float*)(ws + 34603008);          // 1 MB
    bf16*           Bt     = (bf16*)(ws + 35651584);           // 21,504 B (pad 64K)
    unsigned int*   bcount = (unsigned int*)(ws + 35717120);   // 64*2048*4 = 512 KB
    unsigned int*   base   = (unsigned int*)(ws + 36241408);   // 8,196 B (pad 12K)
    unsigned short* eb     = (unsigned short*)(ws + 36253696); // 4,194,304 B

    k0_prep<<<42, 256, 0, stream>>>(W1, Bt);
    k1_mfma<<<NNODES_ / 64, 256, 0, stream>>>(x, Bt, att_src, att_dst, h, as_, ad_);
    kA_hist<<<64, 256, 0, stream>>>(ei, bcount);
    kB_scan<<<1, 256, 0, stream>>>(bcount, base);
    kC_scatter<<<64, 256, 0, stream>>>(ei, bcount, base, eb);
    k3_graph<<<G_, 256, 0, stream>>>(eb, base, h, as_, ad_, b1, Wlin, blin, out);
}

// Round 6
// 390.412 us; speedup vs baseline: 1.6740x; 1.2026x over previous
//
#include <hip/hip_runtime.h>
#include <hip/hip_bf16.h>

#define G_ 2048
#define NPG_ 128
#define INC_ 151
#define HID_ 64
#define NNODES_ (G_ * NPG_)      // 262144
#define NEDGES_ 2097152

typedef __hip_bfloat16 bf16;
typedef short bf16x8v __attribute__((ext_vector_type(8)));
typedef float f32x4 __attribute__((ext_vector_type(4)));

static __device__ __forceinline__ short f2bs(float f) {
    __hip_bfloat16 b = __float2bfloat16(f);
    return __builtin_bit_cast(short, b);
}
static __device__ __forceinline__ float b2f(short s) {
    unsigned int u = ((unsigned int)(unsigned short)s) << 16;
    return __builtin_bit_cast(float, u);
}

// ---------------------------------------------------------------------------
// K0: W1 [151][64] fp32 -> Bt [64 n][168 k] bf16 (k>=151 zero-padded)
// ---------------------------------------------------------------------------
__global__ void __launch_bounds__(256) k0_prep(const float* __restrict__ W1,
                                              bf16* __restrict__ Bt) {
    int i = blockIdx.x * 256 + threadIdx.x;
    if (i >= 64 * 168) return;
    int n = i / 168, k = i - n * 168;
    float v = (k < 151) ? W1[k * 64 + n] : 0.f;
    Bt[i] = __float2bfloat16(v);
}

// ---------------------------------------------------------------------------
// K1 (MFMA): h = x @ W1 bf16, as_[n]=h.att_src, ad_[n]=h.att_dst.
// A-fragments read DIRECTLY from global x (no LDS staging): lane m of quad q
// reads row (base + wv*16 + m), cols ks*32+q*8 .. +7 — each quad covers whole
// 64B lines across 16 rows, 100% line utilization. LDS holds only Bs (21.5KB).
// ---------------------------------------------------------------------------
__global__ void __launch_bounds__(256) k1_mfma(
        const float* __restrict__ x, const bf16* __restrict__ Bt,
        const float* __restrict__ att_src, const float* __restrict__ att_dst,
        bf16* __restrict__ h, float* __restrict__ as_, float* __restrict__ ad_) {
    __shared__ __align__(16) bf16 Bs[64 * 168];
    const int tid = threadIdx.x;
    const int rowbase = blockIdx.x * 64;

    {
        const uint4* s = (const uint4*)Bt;
        uint4* d = (uint4*)Bs;
        for (int i = tid; i < 1344; i += 256) d[i] = s[i];
    }
    __syncthreads();

    const int wv = tid >> 6, lane = tid & 63;
    const int quad = lane >> 4, m = lane & 15;
    const int row = rowbase + wv * 16 + m;
    const float* xr = x + (size_t)row * 151;

    f32x4 acc[4];
#pragma unroll
    for (int t = 0; t < 4; t++) acc[t] = (f32x4){0.f, 0.f, 0.f, 0.f};

#pragma unroll
    for (int ks = 0; ks < 5; ks++) {
        const int k0 = ks * 32 + quad * 8;
        float a[8];
        if (ks < 4) {
#pragma unroll
            for (int e = 0; e < 8; e++) a[e] = xr[k0 + e];
        } else {
#pragma unroll
            for (int e = 0; e < 8; e++) {
                int c = k0 + e;
                a[e] = (c < 151) ? xr[c] : 0.f;
            }
        }
        bf16x8v af = {f2bs(a[0]), f2bs(a[1]), f2bs(a[2]), f2bs(a[3]),
                      f2bs(a[4]), f2bs(a[5]), f2bs(a[6]), f2bs(a[7])};
#pragma unroll
        for (int t = 0; t < 4; t++) {
            bf16x8v bfr = *(const bf16x8v*)&Bs[(t * 16 + m) * 168 + k0];
            acc[t] = __builtin_amdgcn_mfma_f32_16x16x32_bf16(af, bfr, acc[t], 0, 0, 0);
        }
    }

    float as4[4], ad4[4];
#pragma unroll
    for (int t = 0; t < 4; t++) {
        as4[t] = att_src[t * 16 + m];
        ad4[t] = att_dst[t * 16 + m];
    }
#pragma unroll
    for (int r = 0; r < 4; r++) {
        float s = acc[0][r] * as4[0] + acc[1][r] * as4[1] +
                  acc[2][r] * as4[2] + acc[3][r] * as4[3];
        float d = acc[0][r] * ad4[0] + acc[1][r] * ad4[1] +
                  acc[2][r] * ad4[2] + acc[3][r] * ad4[3];
#pragma unroll
        for (int off = 1; off <= 8; off <<= 1) {
            s += __shfl_xor(s, off);
            d += __shfl_xor(d, off);
        }
        const int node = rowbase + wv * 16 + quad * 4 + r;
        if (m == 0) { as_[node] = s; ad_[node] = d; }
#pragma unroll
        for (int t = 0; t < 4; t++) {
            float val = acc[t][r];
            float oth = __shfl_xor(val, 1);
            if (!(lane & 1)) {
                unsigned short lo = (unsigned short)f2bs(val);
                unsigned short hi = (unsigned short)f2bs(oth);
                unsigned int u = ((unsigned int)hi << 16) | lo;
                *(unsigned int*)&h[(size_t)node * 64 + t * 16 + m] = u;
            }
        }
    }
}

// ---------------------------------------------------------------------------
// kA: per-block (256 blocks x 8192 edges) LDS histogram -> bcount[b][g]
// ---------------------------------------------------------------------------
__global__ void __launch_bounds__(256) kA_hist(const int* __restrict__ ei,
                                               unsigned int* __restrict__ bcount) {
    __shared__ unsigned int hist[G_];
    const int tid = threadIdx.x;
    for (int i = tid; i < G_; i += 256) hist[i] = 0;
    __syncthreads();
    const int e0 = blockIdx.x * 8192;
    for (int e = e0 + tid; e < e0 + 8192; e += 256)
        atomicAdd(&hist[ei[e] >> 7], 1u);
    __syncthreads();
    unsigned int* dst = bcount + blockIdx.x * G_;
    for (int i = tid; i < G_; i += 256) dst[i] = hist[i];
}

// ---------------------------------------------------------------------------
// kB1: 8 blocks x 256 threads; thread owns one graph column. Converts
// bcount[b][g] in place to per-block relative offsets; writes gtot[g].
// ---------------------------------------------------------------------------
__global__ void __launch_bounds__(256) kB1_col(unsigned int* __restrict__ bcount,
                                               unsigned int* __restrict__ gtot) {
    const int g = blockIdx.x * 256 + threadIdx.x;
    unsigned int run = 0;
#pragma unroll 4
    for (int b = 0; b < 256; b++) {
        unsigned int* p = &bcount[b * G_ + g];
        unsigned int c = *p;
        *p = run;
        run += c;
    }
    gtot[g] = run;
}

// ---------------------------------------------------------------------------
// kB2: 1 block: exclusive scan of gtot[2048] -> base[2049]
// ---------------------------------------------------------------------------
__global__ void __launch_bounds__(256) kB2_scan(const unsigned int* __restrict__ gtot,
                                                unsigned int* __restrict__ base) {
    __shared__ unsigned int ssum[256];
    const int tid = threadIdx.x;
    const int t8 = tid * 8;
    unsigned int v[8], T = 0;
#pragma unroll
    for (int j = 0; j < 8; j++) { v[j] = gtot[t8 + j]; T += v[j]; }
    ssum[tid] = T;
    __syncthreads();
    for (int off = 1; off < 256; off <<= 1) {
        unsigned int t = (tid >= off) ? ssum[tid - off] : 0;
        __syncthreads();
        ssum[tid] += t;
        __syncthreads();
    }
    unsigned int run = ssum[tid] - T;
#pragma unroll
    for (int j = 0; j < 8; j++) {
        base[t8 + j] = run;
        run += v[j];
    }
    if (tid == 255) base[G_] = run;
}

// ---------------------------------------------------------------------------
// kC: scatter edges to buckets (256 blocks, block-local LDS cursors)
// ---------------------------------------------------------------------------
__global__ void __launch_bounds__(256) kC_scatter(const int* __restrict__ ei,
                                                  const unsigned int* __restrict__ bcount,
                                                  const unsigned int* __restrict__ base,
                                                  unsigned short* __restrict__ eb) {
    __shared__ unsigned int cur[G_];
    const int tid = threadIdx.x;
    const int b = blockIdx.x;
    for (int i = tid; i < G_; i += 256) cur[i] = base[i] + bcount[b * G_ + i];
    __syncthreads();
    const int e0 = b * 8192;
    for (int e = e0 + tid; e < e0 + 8192; e += 256) {
        int s = ei[e];
        int d = ei[NEDGES_ + e];
        int g = s >> 7;
        unsigned int pos = atomicAdd(&cur[g], 1u);
        eb[pos] = (unsigned short)(((s & 127) << 7) | (d & 127));
    }
}

// ---------------------------------------------------------------------------
// K3: one graph per block, MFMA (see round-4 notes). LDS 52224 B static.
// ---------------------------------------------------------------------------
__global__ void __launch_bounds__(256) k3_graph(
        const unsigned short* __restrict__ eb, const unsigned int* __restrict__ base,
        const bf16* __restrict__ h,
        const float* __restrict__ as_, const float* __restrict__ ad_,
        const float* __restrict__ b1, const float* __restrict__ Wlin,
        const float* __restrict__ blin, float* __restrict__ out) {
    __shared__ __align__(16) unsigned char lds[52224];
    short* Ab = (short*)lds;                               // [128][136]
    float* S = (float*)(lds + 34816);                      // [32][128]
    short* hT = (short*)(lds + 34816);                     // [64][136]
    unsigned short* ec = (unsigned short*)(lds + 30720);   // [2048]

    const int tid = threadIdx.x;
    const int g = blockIdx.x;
    const unsigned int gb = base[g], ge = base[g + 1];
    const float* asg = as_ + (g << 7);
    const float* adg = ad_ + (g << 7);
    const unsigned int* hgu = (const unsigned int*)(h + ((size_t)g << 13));

    const unsigned int cnt = ge - gb;
    const unsigned int ccnt = cnt > 2048u ? 2048u : cnt;
    for (unsigned int k = tid; k < ccnt; k += 256) ec[k] = eb[gb + k];
    __syncthreads();

#pragma unroll 1
    for (int p = 0; p < 4; p++) {
        for (int i = tid; i < 1024; i += 256)
            ((float4*)S)[i] = make_float4(0.f, 0.f, 0.f, 0.f);
        __syncthreads();
        for (unsigned int k = tid; k < ccnt; k += 256) {
            unsigned int v = ec[k];
            int sl = v >> 7, dl = v & 127;
            if ((dl >> 5) == p) {
                float a = asg[sl] + adg[dl];
                a = (a > 0.f) ? a : 0.2f * a;
                atomicAdd(&S[((dl & 31) << 7) + sl], __expf(a));
            }
        }
        for (unsigned int k = gb + ccnt + tid; k < ge; k += 256) {
            unsigned int v = eb[k];
            int sl = v >> 7, dl = v & 127;
            if ((dl >> 5) == p) {
                float a = asg[sl] + adg[dl];
                a = (a > 0.f) ? a : 0.2f * a;
                atomicAdd(&S[((dl & 31) << 7) + sl], __expf(a));
            }
        }
        __syncthreads();
        for (int c = tid; c < 512; c += 256) {
            int r = c >> 4;
            int col = (c & 15) << 3;
            float4 v0 = ((const float4*)S)[c * 2];
            float4 v1 = ((const float4*)S)[c * 2 + 1];
            bf16x8v pk = {f2bs(v0.x), f2bs(v0.y), f2bs(v0.z), f2bs(v0.w),
                          f2bs(v1.x), f2bs(v1.y), f2bs(v1.z), f2bs(v1.w)};
            *(bf16x8v*)&Ab[(32 * p + r) * 136 + col] = pk;
        }
        __syncthreads();
    }

    if (tid < 128) {
        float a = asg[tid] + adg[tid];
        a = (a > 0.f) ? a : 0.2f * a;
        Ab[tid * 136 + tid] = f2bs(b2f(Ab[tid * 136 + tid]) + __expf(a));
    }
    __syncthreads();

    const int ri = tid >> 1, rh = tid & 1;
    {
        const bf16x8v* rp = (const bf16x8v*)&Ab[ri * 136 + rh * 64];
        float s = 0.f;
#pragma unroll
        for (int q8 = 0; q8 < 8; q8++) {
            bf16x8v v = rp[q8];
#pragma unroll
            for (int e = 0; e < 8; e++) s += b2f(v[e]);
        }
        S[tid] = s;
    }
    __syncthreads();
    {
        float inv = 1.f / (S[ri * 2] + S[ri * 2 + 1]);
        bf16x8v* wp = (bf16x8v*)&Ab[ri * 136 + rh * 64];
#pragma unroll
        for (int q8 = 0; q8 < 8; q8++) {
            bf16x8v v = wp[q8];
            bf16x8v o;
#pragma unroll
            for (int e = 0; e < 8; e++) o[e] = f2bs(b2f(v[e]) * inv);
            wp[q8] = o;
        }
    }
    __syncthreads();

    for (int idx = tid; idx < 4096; idx += 256) {
        unsigned int u = hgu[idx];
        int j = idx >> 5, f2 = idx & 31;
        hT[(2 * f2) * 136 + j] = (short)(u & 0xFFFF);
        hT[(2 * f2 + 1) * 136 + j] = (short)(u >> 16);
    }
    __syncthreads();

    const int w = tid >> 6, lane = tid & 63;
    const int quad = lane >> 4, m = lane & 15;
    const int i0 = w * 32;
    f32x4 acc[2][4];
#pragma unroll
    for (int mt = 0; mt < 2; mt++)
#pragma unroll
        for (int nt = 0; nt < 4; nt++) acc[mt][nt] = (f32x4){0.f, 0.f, 0.f, 0.f};

#pragma unroll
    for (int ks = 0; ks < 4; ks++) {
        const int k0 = ks * 32 + quad * 8;
        bf16x8v a0 = *(const bf16x8v*)&Ab[(i0 + m) * 136 + k0];
        bf16x8v a1 = *(const bf16x8v*)&Ab[(i0 + 16 + m) * 136 + k0];
#pragma unroll
        for (int nt = 0; nt < 4; nt++) {
            bf16x8v bfr = *(const bf16x8v*)&hT[(nt * 16 + m) * 136 + k0];
            acc[0][nt] = __builtin_amdgcn_mfma_f32_16x16x32_bf16(a0, bfr, acc[0][nt], 0, 0, 0);
            acc[1][nt] = __builtin_amdgcn_mfma_f32_16x16x32_bf16(a1, bfr, acc[1][nt], 0, 0, 0);
        }
    }

    float p = 0.f;
#pragma unroll
    for (int nt = 0; nt < 4; nt++) {
        float bb = b1[nt * 16 + m];
#pragma unroll
        for (int mt = 0; mt < 2; mt++) {
#pragma unroll
            for (int r = 0; r < 4; r++) {
                int il = i0 + mt * 16 + quad * 4 + r;
                float v = acc[mt][nt][r] + bb;
                v = v > 0.f ? v : 0.f;
                p += v * Wlin[il * 64 + nt * 16 + m];
            }
        }
    }
#pragma unroll
    for (int off = 32; off; off >>= 1) p += __shfl_xor(p, off);

    __syncthreads();
    if (lane == 0) S[w] = p;
    __syncthreads();
    if (tid == 0) {
        float logit = S[0] + S[1] + S[2] + S[3] + blin[0];
        out[g] = 1.f / (1.f + __expf(-logit));
    }
}

// ---------------------------------------------------------------------------
extern "C" void kernel_launch(void* const* d_in, const int* in_sizes, int n_in,
                              void* d_out, int out_size, void* d_ws, size_t ws_size,
                              hipStream_t stream) {
    (void)in_sizes; (void)n_in; (void)out_size; (void)ws_size;
    const float* x       = (const float*)d_in[0];
    const int*   ei      = (const int*)d_in[1];
    const float* W1      = (const float*)d_in[2];
    const float* att_src = (const float*)d_in[3];
    const float* att_dst = (const float*)d_in[4];
    const float* b1      = (const float*)d_in[5];
    const float* Wlin    = (const float*)d_in[6];
    const float* blin    = (const float*)d_in[7];
    float* out = (float*)d_out;

    char* ws = (char*)d_ws;
    bf16*           h      = (bf16*)ws;                        // 33,554,432 B
    float*          as_    = (float*)(ws + 33554432);          // 1 MB
    float*          ad_    = (float*)(ws + 34603008);          // 1 MB
    bf16*           Bt     = (bf16*)(ws + 35651584);           // 21,504 (pad 64K)
    unsigned int*   bcount = (unsigned int*)(ws + 35717120);   // 256*2048*4 = 2 MB
    unsigned int*   gtot   = (unsigned int*)(ws + 37814272);   // 8 KB
    unsigned int*   base   = (unsigned int*)(ws + 37822464);   // 8,196 (pad 12K)
    unsigned short* eb     = (unsigned short*)(ws + 37834752); // 4,194,304 B

    k0_prep<<<42, 256, 0, stream>>>(W1, Bt);
    k1_mfma<<<NNODES_ / 64, 256, 0, stream>>>(x, Bt, att_src, att_dst, h, as_, ad_);
    kA_hist<<<256, 256, 0, stream>>>(ei, bcount);
    kB1_col<<<8, 256, 0, stream>>>(bcount, gtot);
    kB2_scan<<<1, 256, 0, stream>>>(gtot, base);
    kC_scatter<<<256, 256, 0, stream>>>(ei, bcount, base, eb);
    k3_graph<<<G_, 256, 0, stream>>>(eb, base, h, as_, ad_, b1, Wlin, blin, out);
}

// Round 7
// 389.810 us; speedup vs baseline: 1.6766x; 1.0015x over previous
//
#include <hip/hip_runtime.h>
#include <hip/hip_bf16.h>

#define G_ 2048
#define NPG_ 128
#define INC_ 151
#define HID_ 64
#define NNODES_ (G_ * NPG_)      // 262144
#define NEDGES_ 2097152

typedef __hip_bfloat16 bf16;
typedef short bf16x8v __attribute__((ext_vector_type(8)));
typedef float f32x4 __attribute__((ext_vector_type(4)));

static __device__ __forceinline__ short f2bs(float f) {
    __hip_bfloat16 b = __float2bfloat16(f);
    return __builtin_bit_cast(short, b);
}
static __device__ __forceinline__ float b2f(short s) {
    unsigned int u = ((unsigned int)(unsigned short)s) << 16;
    return __builtin_bit_cast(float, u);
}

// ---------------------------------------------------------------------------
// K0: W1 [151][64] fp32 -> Bt [64 n][168 k] bf16 (k>=151 zero-padded)
// ---------------------------------------------------------------------------
__global__ void __launch_bounds__(256) k0_prep(const float* __restrict__ W1,
                                              bf16* __restrict__ Bt) {
    int i = blockIdx.x * 256 + threadIdx.x;
    if (i >= 64 * 168) return;
    int n = i / 168, k = i - n * 168;
    float v = (k < 151) ? W1[k * 64 + n] : 0.f;
    Bt[i] = __float2bfloat16(v);
}

// ---------------------------------------------------------------------------
// K1 (MFMA): h = x @ W1 bf16, as_[n]=h.att_src, ad_[n]=h.att_dst.
// A-fragments read directly from global x; LDS holds only Bs (21.5KB).
// ---------------------------------------------------------------------------
__global__ void __launch_bounds__(256) k1_mfma(
        const float* __restrict__ x, const bf16* __restrict__ Bt,
        const float* __restrict__ att_src, const float* __restrict__ att_dst,
        bf16* __restrict__ h, float* __restrict__ as_, float* __restrict__ ad_) {
    __shared__ __align__(16) bf16 Bs[64 * 168];
    const int tid = threadIdx.x;
    const int rowbase = blockIdx.x * 64;

    {
        const uint4* s = (const uint4*)Bt;
        uint4* d = (uint4*)Bs;
        for (int i = tid; i < 1344; i += 256) d[i] = s[i];
    }
    __syncthreads();

    const int wv = tid >> 6, lane = tid & 63;
    const int quad = lane >> 4, m = lane & 15;
    const int row = rowbase + wv * 16 + m;
    const float* xr = x + (size_t)row * 151;

    f32x4 acc[4];
#pragma unroll
    for (int t = 0; t < 4; t++) acc[t] = (f32x4){0.f, 0.f, 0.f, 0.f};

#pragma unroll
    for (int ks = 0; ks < 5; ks++) {
        const int k0 = ks * 32 + quad * 8;
        float a[8];
        if (ks < 4) {
#pragma unroll
            for (int e = 0; e < 8; e++) a[e] = xr[k0 + e];
        } else {
#pragma unroll
            for (int e = 0; e < 8; e++) {
                int c = k0 + e;
                a[e] = (c < 151) ? xr[c] : 0.f;
            }
        }
        bf16x8v af = {f2bs(a[0]), f2bs(a[1]), f2bs(a[2]), f2bs(a[3]),
                      f2bs(a[4]), f2bs(a[5]), f2bs(a[6]), f2bs(a[7])};
#pragma unroll
        for (int t = 0; t < 4; t++) {
            bf16x8v bfr = *(const bf16x8v*)&Bs[(t * 16 + m) * 168 + k0];
            acc[t] = __builtin_amdgcn_mfma_f32_16x16x32_bf16(af, bfr, acc[t], 0, 0, 0);
        }
    }

    float as4[4], ad4[4];
#pragma unroll
    for (int t = 0; t < 4; t++) {
        as4[t] = att_src[t * 16 + m];
        ad4[t] = att_dst[t * 16 + m];
    }
#pragma unroll
    for (int r = 0; r < 4; r++) {
        float s = acc[0][r] * as4[0] + acc[1][r] * as4[1] +
                  acc[2][r] * as4[2] + acc[3][r] * as4[3];
        float d = acc[0][r] * ad4[0] + acc[1][r] * ad4[1] +
                  acc[2][r] * ad4[2] + acc[3][r] * ad4[3];
#pragma unroll
        for (int off = 1; off <= 8; off <<= 1) {
            s += __shfl_xor(s, off);
            d += __shfl_xor(d, off);
        }
        const int node = rowbase + wv * 16 + quad * 4 + r;
        if (m == 0) { as_[node] = s; ad_[node] = d; }
#pragma unroll
        for (int t = 0; t < 4; t++) {
            float val = acc[t][r];
            float oth = __shfl_xor(val, 1);
            if (!(lane & 1)) {
                unsigned short lo = (unsigned short)f2bs(val);
                unsigned short hi = (unsigned short)f2bs(oth);
                unsigned int u = ((unsigned int)hi << 16) | lo;
                *(unsigned int*)&h[(size_t)node * 64 + t * 16 + m] = u;
            }
        }
    }
}

// ---------------------------------------------------------------------------
// kC1: coarse histogram (bucket = g>>3, 256 buckets) -> bccount[b][256]
// ---------------------------------------------------------------------------
__global__ void __launch_bounds__(256) kC1_hist(const int* __restrict__ ei,
                                                unsigned int* __restrict__ bccount) {
    __shared__ unsigned int hist[256];
    const int tid = threadIdx.x;
    hist[tid] = 0;
    __syncthreads();
    const int e0 = blockIdx.x * 8192;
    for (int e = e0 + tid; e < e0 + 8192; e += 256)
        atomicAdd(&hist[ei[e] >> 10], 1u);
    __syncthreads();
    bccount[blockIdx.x * 256 + tid] = hist[tid];
}

// ---------------------------------------------------------------------------
// kC2: 1 block. bccount[b][bk] -> per-block relative offsets (in place);
// cbase[bk] = exclusive scan of bucket totals; cbase[256]=E; base[2048]=E.
// ---------------------------------------------------------------------------
__global__ void __launch_bounds__(256) kC2_scan(unsigned int* __restrict__ bccount,
                                                unsigned int* __restrict__ cbase,
                                                unsigned int* __restrict__ base) {
    __shared__ unsigned int ssum[256];
    const int tid = threadIdx.x;
    unsigned int run = 0;
#pragma unroll 4
    for (int b = 0; b < 256; b++) {
        unsigned int* p = &bccount[b * 256 + tid];
        unsigned int c = *p;
        *p = run;
        run += c;
    }
    ssum[tid] = run;
    __syncthreads();
    unsigned int tot = run;
    for (int off = 1; off < 256; off <<= 1) {
        unsigned int t = (tid >= off) ? ssum[tid - off] : 0;
        __syncthreads();
        ssum[tid] += t;
        __syncthreads();
    }
    cbase[tid] = ssum[tid] - tot;
    if (tid == 255) {
        cbase[256] = ssum[255];
        base[G_] = NEDGES_;
    }
}

// ---------------------------------------------------------------------------
// kC3: scatter u32 records ((s&1023)<<7 | dl) to coarse buckets.
// Runs of ~32 consecutive u32 per (block,bucket) -> good write combining.
// ---------------------------------------------------------------------------
__global__ void __launch_bounds__(256) kC3_scatter(const int* __restrict__ ei,
                                                   const unsigned int* __restrict__ bccount,
                                                   const unsigned int* __restrict__ cbase,
                                                   unsigned int* __restrict__ rbuf) {
    __shared__ unsigned int cur[256];
    const int tid = threadIdx.x;
    cur[tid] = cbase[tid] + bccount[blockIdx.x * 256 + tid];
    __syncthreads();
    const int e0 = blockIdx.x * 8192;
    for (int e = e0 + tid; e < e0 + 8192; e += 256) {
        int s = ei[e];
        int d = ei[NEDGES_ + e];
        int bk = s >> 10;
        unsigned int pos = atomicAdd(&cur[bk], 1u);
        rbuf[pos] = (((unsigned int)s & 1023u) << 7) | ((unsigned int)d & 127u);
    }
}

// ---------------------------------------------------------------------------
// kC4: per coarse bucket (8 graphs): local counts -> base[g]; write final eb
// u16 in per-graph contiguous runs. Ballot-aggregated LDS cursors.
// ---------------------------------------------------------------------------
__global__ void __launch_bounds__(256) kC4_fine(const unsigned int* __restrict__ rbuf,
                                                const unsigned int* __restrict__ cbase,
                                                unsigned int* __restrict__ base,
                                                unsigned short* __restrict__ eb) {
    __shared__ unsigned int lcnt[8];
    __shared__ unsigned int cur[8];
    const int tid = threadIdx.x;
    const int b = blockIdx.x;
    const unsigned int s0 = cbase[b], s1 = cbase[b + 1];
    if (tid < 8) lcnt[tid] = 0;
    __syncthreads();
    for (unsigned int i = s0 + tid; i < s1; i += 256)
        atomicAdd(&lcnt[(rbuf[i] >> 14) & 7], 1u);
    __syncthreads();
    if (tid == 0) {
        unsigned int r = 0;
#pragma unroll
        for (int j = 0; j < 8; j++) {
            base[b * 8 + j] = s0 + r;
            cur[j] = s0 + r;
            r += lcnt[j];
        }
    }
    __syncthreads();
    const int lane = tid & 63;
    for (unsigned int i = s0 + tid; i < s1; i += 256) {
        unsigned int rec = rbuf[i];
        int gl = (rec >> 14) & 7;
        unsigned long long act = __ballot(1);
        unsigned long long b0 = __ballot(gl & 1);
        unsigned long long b1 = __ballot(gl & 2);
        unsigned long long b2 = __ballot(gl & 4);
        unsigned long long m = ((gl & 1) ? b0 : ~b0) &
                               ((gl & 2) ? b1 : ~b1) &
                               ((gl & 4) ? b2 : ~b2) & act;
        int leader = __builtin_ctzll(m);
        int rank = __builtin_popcountll(m & ((1ull << lane) - 1ull));
        unsigned int bp = 0;
        if (lane == leader)
            bp = atomicAdd(&cur[gl], (unsigned int)__builtin_popcountll(m));
        bp = __shfl((int)bp, leader);
        eb[bp + rank] = (unsigned short)(rec & 0x3FFFu);
    }
}

// ---------------------------------------------------------------------------
// K3: one graph per block, MFMA. Denominators folded into epilogue (dinv).
// LDS 52736 B static (3 blocks/CU):
//   Ab  bf16 [128][136]  @0       (34816)
//   S   fp32 [32][128]   @34816   (16384)  build accum (per 32-dst-row pass)
//   hT  bf16 [64][136]   @34816   (17408)  staged after build (union with S)
//   ec  u16  [2048]      @30720   (4096)   edge cache; clobbered by pass-3 convert
//   dinv fp32[128]       @52224   (512)
// ---------------------------------------------------------------------------
__global__ void __launch_bounds__(256) k3_graph(
        const unsigned short* __restrict__ eb, const unsigned int* __restrict__ base,
        const bf16* __restrict__ h,
        const float* __restrict__ as_, const float* __restrict__ ad_,
        const float* __restrict__ b1, const float* __restrict__ Wlin,
        const float* __restrict__ blin, float* __restrict__ out) {
    __shared__ __align__(16) unsigned char lds[52736];
    short* Ab = (short*)lds;                               // [128][136]
    float* S = (float*)(lds + 34816);                      // [32][128]
    short* hT = (short*)(lds + 34816);                     // [64][136]
    unsigned short* ec = (unsigned short*)(lds + 30720);   // [2048]
    float* dinv = (float*)(lds + 52224);                   // [128]

    const int tid = threadIdx.x;
    const int g = blockIdx.x;
    const unsigned int gb = base[g], ge = base[g + 1];
    const float* asg = as_ + (g << 7);
    const float* adg = ad_ + (g << 7);
    const unsigned int* hgu = (const unsigned int*)(h + ((size_t)g << 13));

    const unsigned int cnt = ge - gb;
    const unsigned int ccnt = cnt > 2048u ? 2048u : cnt;
    for (unsigned int k = tid; k < ccnt; k += 256) ec[k] = eb[gb + k];
    __syncthreads();

    // build A[dst][src] = exp(leakyrelu(alpha)) in 4 passes of 32 dst rows,
    // self-loops injected in-pass; fp32 row sums -> dinv per pass.
#pragma unroll 1
    for (int p = 0; p < 4; p++) {
        for (int i = tid; i < 1024; i += 256)
            ((float4*)S)[i] = make_float4(0.f, 0.f, 0.f, 0.f);
        __syncthreads();
        if (tid < 32) {
            int node = 32 * p + tid;
            float a = asg[node] + adg[node];
            a = (a > 0.f) ? a : 0.2f * a;
            atomicAdd(&S[(tid << 7) + node], __expf(a));
        }
        for (unsigned int k = tid; k < ccnt; k += 256) {
            unsigned int v = ec[k];
            int sl = v >> 7, dl = v & 127;
            if ((dl >> 5) == p) {
                float a = asg[sl] + adg[dl];
                a = (a > 0.f) ? a : 0.2f * a;
                atomicAdd(&S[((dl & 31) << 7) + sl], __expf(a));
            }
        }
        for (unsigned int k = gb + ccnt + tid; k < ge; k += 256) {  // overflow
            unsigned int v = eb[k];
            int sl = v >> 7, dl = v & 127;
            if ((dl >> 5) == p) {
                float a = asg[sl] + adg[dl];
                a = (a > 0.f) ? a : 0.2f * a;
                atomicAdd(&S[((dl & 31) << 7) + sl], __expf(a));
            }
        }
        __syncthreads();
        // row sums: 8 lanes per row (16 floats each), shfl-combine
        {
            const float4* rp = (const float4*)&S[((tid >> 3) << 7) + ((tid & 7) << 4)];
            float s = 0.f;
#pragma unroll
            for (int q = 0; q < 4; q++) {
                float4 v = rp[q];
                s += v.x + v.y + v.z + v.w;
            }
            s += __shfl_xor(s, 1);
            s += __shfl_xor(s, 2);
            s += __shfl_xor(s, 4);
            if ((tid & 7) == 0) dinv[32 * p + (tid >> 3)] = 1.f / s;
        }
        // convert S[32][128] -> Ab rows 32p..32p+31 (bf16, stride 136)
        for (int c = tid; c < 512; c += 256) {
            int r = c >> 4;
            int col = (c & 15) << 3;
            float4 v0 = ((const float4*)S)[c * 2];
            float4 v1 = ((const float4*)S)[c * 2 + 1];
            bf16x8v pk = {f2bs(v0.x), f2bs(v0.y), f2bs(v0.z), f2bs(v0.w),
                          f2bs(v1.x), f2bs(v1.y), f2bs(v1.z), f2bs(v1.w)};
            *(bf16x8v*)&Ab[(32 * p + r) * 136 + col] = pk;
        }
        __syncthreads();
    }

    // stage hT[f][j] (transposed, stride 136) from h[j][f]
    for (int idx = tid; idx < 4096; idx += 256) {
        unsigned int u = hgu[idx];
        int j = idx >> 5, f2 = idx & 31;
        hT[(2 * f2) * 136 + j] = (short)(u & 0xFFFF);
        hT[(2 * f2 + 1) * 136 + j] = (short)(u >> 16);
    }
    __syncthreads();

    // MFMA: wave w -> rows i0=w*32 (2 M-tiles), 4 N-tiles, K=128 (4 steps)
    const int w = tid >> 6, lane = tid & 63;
    const int quad = lane >> 4, m = lane & 15;
    const int i0 = w * 32;
    f32x4 acc[2][4];
#pragma unroll
    for (int mt = 0; mt < 2; mt++)
#pragma unroll
        for (int nt = 0; nt < 4; nt++) acc[mt][nt] = (f32x4){0.f, 0.f, 0.f, 0.f};

#pragma unroll
    for (int ks = 0; ks < 4; ks++) {
        const int k0 = ks * 32 + quad * 8;
        bf16x8v a0 = *(const bf16x8v*)&Ab[(i0 + m) * 136 + k0];
        bf16x8v a1 = *(const bf16x8v*)&Ab[(i0 + 16 + m) * 136 + k0];
#pragma unroll
        for (int nt = 0; nt < 4; nt++) {
            bf16x8v bfr = *(const bf16x8v*)&hT[(nt * 16 + m) * 136 + k0];
            acc[0][nt] = __builtin_amdgcn_mfma_f32_16x16x32_bf16(a0, bfr, acc[0][nt], 0, 0, 0);
            acc[1][nt] = __builtin_amdgcn_mfma_f32_16x16x32_bf16(a1, bfr, acc[1][nt], 0, 0, 0);
        }
    }

    // epilogue: relu(acc*dinv + b1) . Wlin
    float dv[2][4];
#pragma unroll
    for (int mt = 0; mt < 2; mt++)
#pragma unroll
        for (int r = 0; r < 4; r++)
            dv[mt][r] = dinv[i0 + mt * 16 + quad * 4 + r];

    float p = 0.f;
#pragma unroll
    for (int nt = 0; nt < 4; nt++) {
        float bb = b1[nt * 16 + m];
#pragma unroll
        for (int mt = 0; mt < 2; mt++) {
#pragma unroll
            for (int r = 0; r < 4; r++) {
                int il = i0 + mt * 16 + quad * 4 + r;
                float v = acc[mt][nt][r] * dv[mt][r] + bb;
                v = v > 0.f ? v : 0.f;
                p += v * Wlin[il * 64 + nt * 16 + m];
            }
        }
    }
#pragma unroll
    for (int off = 32; off; off >>= 1) p += __shfl_xor(p, off);

    __syncthreads();
    if (lane == 0) S[w] = p;
    __syncthreads();
    if (tid == 0) {
        float logit = S[0] + S[1] + S[2] + S[3] + blin[0];
        out[g] = 1.f / (1.f + __expf(-logit));
    }
}

// ---------------------------------------------------------------------------
extern "C" void kernel_launch(void* const* d_in, const int* in_sizes, int n_in,
                              void* d_out, int out_size, void* d_ws, size_t ws_size,
                              hipStream_t stream) {
    (void)in_sizes; (void)n_in; (void)out_size; (void)ws_size;
    const float* x       = (const float*)d_in[0];
    const int*   ei      = (const int*)d_in[1];
    const float* W1      = (const float*)d_in[2];
    const float* att_src = (const float*)d_in[3];
    const float* att_dst = (const float*)d_in[4];
    const float* b1      = (const float*)d_in[5];
    const float* Wlin    = (const float*)d_in[6];
    const float* blin    = (const float*)d_in[7];
    float* out = (float*)d_out;

    char* ws = (char*)d_ws;
    bf16*           h       = (bf16*)ws;                        // 33,554,432 B
    float*          as_     = (float*)(ws + 33554432);          // 1 MB
    float*          ad_     = (float*)(ws + 34603008);          // 1 MB
    bf16*           Bt      = (bf16*)(ws + 35651584);           // 21,504 (pad 64K)
    unsigned int*   bccount = (unsigned int*)(ws + 35717120);   // 256*256*4 = 256 KB
    unsigned int*   cbase   = (unsigned int*)(ws + 35979264);   // 1,028 (pad 4K)
    unsigned int*   base    = (unsigned int*)(ws + 35983360);   // 8,196 (pad 12K)
    unsigned int*   rbuf    = (unsigned int*)(ws + 35995648);   // 8,388,608
    unsigned short* eb      = (unsigned short*)(ws + 44384256); // 4,194,304

    k0_prep<<<42, 256, 0, stream>>>(W1, Bt);
    k1_mfma<<<NNODES_ / 64, 256, 0, stream>>>(x, Bt, att_src, att_dst, h, as_, ad_);
    kC1_hist<<<256, 256, 0, stream>>>(ei, bccount);
    kC2_scan<<<1, 256, 0, stream>>>(bccount, cbase, base);
    kC3_scatter<<<256, 256, 0, stream>>>(ei, bccount, cbase, rbuf);
    kC4_fine<<<256, 256, 0, stream>>>(rbuf, cbase, base, eb);
    k3_graph<<<G_, 256, 0, stream>>>(eb, base, h, as_, ad_, b1, Wlin, blin, out);
}